// Round 1
// 292.327 us; speedup vs baseline: 1.2849x; 1.2849x over previous
//
#include <hip/hip_runtime.h>

// Problem constants (from reference): x = (32, 256, 56, 56) fp32
#define M_BATCH 32
#define D_FEAT 256
#define HW 3136              // 56*56
#define HW4 784              // HW/4, float4 elements per channel
#define NGROUPS 16
#define GS 16
#define NTOT (M_BATCH * HW)  // 100352 samples per channel
#define TRI 136              // 16*17/2 packed lower triangle
#define EPS_W 1e-6f

// Sample-dimension split: grid (32,16,SPLIT) -> 1024 one-wave blocks
// = exactly 1 wave per SIMD on 256 CUs (one full-machine round).
#define SPLIT 2
#define SLICE4 (HW4 / SPLIT)          // 392 float4 per slice
#define NIT ((SLICE4 + 63) / 64)      // 7 iterations per lane

__device__ __host__ constexpr int tidx(int i, int j) { return i * (i + 1) / 2 + j; }

// ---------------------------------------------------------------------------
// Pass 1: per-channel sums + per-group packed Gram accumulators.
// One WAVE per (batch, group, slice). launch_bounds(64,1) -> VGPR cap 512 so
// the 136 accumulators + double-buffered float4 staging ALL live in registers
// (previous version spilled ~60 accs to scratch at VGPR=108 -> 168us).
// ---------------------------------------------------------------------------
__device__ __forceinline__ void accum16(const float4 (&v)[GS], float (&acc)[TRI],
                                        float (&sv)[GS]) {
#pragma unroll
    for (int i = 0; i < GS; ++i) {
        sv[i] += (v[i].x + v[i].y) + (v[i].z + v[i].w);
#pragma unroll
        for (int j = 0; j <= i; ++j) {
            float t = acc[tidx(i, j)];
            t = fmaf(v[i].x, v[j].x, t);
            t = fmaf(v[i].y, v[j].y, t);
            t = fmaf(v[i].z, v[j].z, t);
            t = fmaf(v[i].w, v[j].w, t);
            acc[tidx(i, j)] = t;
        }
    }
}

__global__ __launch_bounds__(64, 1) void whiten_stats(const float4* __restrict__ x4,
                                                      float* __restrict__ sums,
                                                      float* __restrict__ gram) {
    const int b = blockIdx.x;
    const int g = blockIdx.y;
    const int s = blockIdx.z;
    const int lane = threadIdx.x;

    const unsigned cbase = ((unsigned)b * D_FEAT + (unsigned)g * GS) * HW4;
    const unsigned p0 = (unsigned)s * SLICE4 + (unsigned)lane;
    const unsigned pend = (unsigned)(s + 1) * SLICE4;

    float acc[TRI];
    float sv[GS];
#pragma unroll
    for (int k = 0; k < TRI; ++k) acc[k] = 0.0f;
#pragma unroll
    for (int j = 0; j < GS; ++j) sv[j] = 0.0f;

    const float4 z4 = make_float4(0.0f, 0.0f, 0.0f, 0.0f);
    float4 v[GS], w[GS];

    unsigned p = p0;
#pragma unroll
    for (int j = 0; j < GS; ++j)
        v[j] = (p < pend) ? x4[cbase + (unsigned)j * HW4 + p] : z4;

#pragma unroll 1
    for (int it = 1; it < NIT; ++it) {
        const unsigned pn = p0 + (unsigned)it * 64u;
        // issue next-chunk loads (fly during compute below)
#pragma unroll
        for (int j = 0; j < GS; ++j)
            w[j] = (pn < pend) ? x4[cbase + (unsigned)j * HW4 + pn] : z4;

        accum16(v, acc, sv);

#pragma unroll
        for (int j = 0; j < GS; ++j) v[j] = w[j];
        p = pn;
    }
    accum16(v, acc, sv);

    // wave-level shuffle reduction, one atomic per wave per cell
#pragma unroll
    for (int j = 0; j < GS; ++j) {
        float r = sv[j];
#pragma unroll
        for (int off = 32; off > 0; off >>= 1) r += __shfl_down(r, off, 64);
        if (lane == 0) atomicAdd(&sums[g * GS + j], r);
    }
#pragma unroll
    for (int k = 0; k < TRI; ++k) {
        float r = acc[k];
#pragma unroll
        for (int off = 32; off > 0; off >>= 1) r += __shfl_down(r, off, 64);
        if (lane == 0) atomicAdd(&gram[g * TRI + k], r);
    }
}

// ---------------------------------------------------------------------------
// Pass 2: sigma -> Cholesky -> inv(T), all 16 groups in parallel lanes of one
// wave. launch_bounds(64,1) so S[136]+mu[16] stay in registers here too.
// ---------------------------------------------------------------------------
__global__ __launch_bounds__(64, 1) void whiten_solve(const float* __restrict__ sums,
                                                      const float* __restrict__ gram,
                                                      float* __restrict__ wout,
                                                      float* __restrict__ muout) {
    const int g = threadIdx.x;
    if (g >= NGROUPS) return;

    float mu[GS];
#pragma unroll
    for (int j = 0; j < GS; ++j) mu[j] = sums[g * GS + j] * (1.0f / (float)NTOT);

    float S[TRI];
#pragma unroll
    for (int i = 0; i < GS; ++i) {
#pragma unroll
        for (int j = 0; j <= i; ++j) {
            float sg = (gram[g * TRI + tidx(i, j)] - (float)NTOT * mu[i] * mu[j])
                       * (1.0f / (float)(NTOT - 1));
            sg *= (1.0f - EPS_W);
            if (i == j) sg += EPS_W;
            S[tidx(i, j)] = sg;
        }
    }

    // In-place Cholesky (Crout): S becomes T (lower).
#pragma unroll
    for (int c = 0; c < GS; ++c) {
        float d = S[tidx(c, c)];
#pragma unroll
        for (int k = 0; k < c; ++k) d -= S[tidx(c, k)] * S[tidx(c, k)];
        d = sqrtf(d);
        S[tidx(c, c)] = d;
        const float inv = 1.0f / d;
#pragma unroll
        for (int i = c + 1; i < GS; ++i) {
            float t = S[tidx(i, c)];
#pragma unroll
            for (int k = 0; k < c; ++k) t -= S[tidx(i, k)] * S[tidx(c, k)];
            S[tidx(i, c)] = t * inv;
        }
    }

    // In-place inverse of lower-triangular T: S becomes W = T^{-1}.
#pragma unroll
    for (int c = 0; c < GS; ++c) {
        const float wcc = 1.0f / S[tidx(c, c)];
        S[tidx(c, c)] = wcc;
#pragma unroll
        for (int i = c + 1; i < GS; ++i) {
            float a = 0.0f;
#pragma unroll
            for (int k = c; k < i; ++k) a += S[tidx(i, k)] * S[tidx(k, c)];
            S[tidx(i, c)] = -a / S[tidx(i, i)];
        }
    }

#pragma unroll
    for (int k = 0; k < TRI; ++k) wout[g * TRI + k] = S[k];
#pragma unroll
    for (int j = 0; j < GS; ++j) muout[g * GS + j] = mu[j];
}

// ---------------------------------------------------------------------------
// Pass 3: out = W * (x - mu). Same one-wave-per-block register scheme:
// w[136]+mu[16]+double-buffered float4 staging ~ 300 VGPR, no spill.
// ---------------------------------------------------------------------------
__global__ __launch_bounds__(64, 1) void whiten_apply(const float4* __restrict__ x4,
                                                      const float* __restrict__ wmat,
                                                      const float* __restrict__ mu,
                                                      float4* __restrict__ out4) {
    const int b = blockIdx.x;
    const int g = blockIdx.y;
    const int s = blockIdx.z;
    const int lane = threadIdx.x;

    float wv[TRI], mv[GS];
#pragma unroll
    for (int k = 0; k < TRI; ++k) wv[k] = wmat[g * TRI + k];
#pragma unroll
    for (int j = 0; j < GS; ++j) mv[j] = mu[g * GS + j];

    const unsigned cbase = ((unsigned)b * D_FEAT + (unsigned)g * GS) * HW4;
    const unsigned p0 = (unsigned)s * SLICE4 + (unsigned)lane;
    const unsigned pend = (unsigned)(s + 1) * SLICE4;

    const float4 z4 = make_float4(0.0f, 0.0f, 0.0f, 0.0f);
    float4 v[GS], w[GS];

    unsigned p = p0;
#pragma unroll
    for (int j = 0; j < GS; ++j)
        v[j] = (p < pend) ? x4[cbase + (unsigned)j * HW4 + p] : z4;

#pragma unroll 1
    for (int it = 1; it < NIT; ++it) {
        const unsigned pn = p0 + (unsigned)it * 64u;
#pragma unroll
        for (int j = 0; j < GS; ++j)
            w[j] = (pn < pend) ? x4[cbase + (unsigned)j * HW4 + pn] : z4;

        // center, then triangular matvec + store
#pragma unroll
        for (int j = 0; j < GS; ++j) {
            v[j].x -= mv[j]; v[j].y -= mv[j]; v[j].z -= mv[j]; v[j].w -= mv[j];
        }
        if (p < pend) {
#pragma unroll
            for (int i = 0; i < GS; ++i) {
                float4 a;
                a.x = wv[tidx(i, 0)] * v[0].x;
                a.y = wv[tidx(i, 0)] * v[0].y;
                a.z = wv[tidx(i, 0)] * v[0].z;
                a.w = wv[tidx(i, 0)] * v[0].w;
#pragma unroll
                for (int j = 1; j <= i; ++j) {
                    const float wc = wv[tidx(i, j)];
                    a.x = fmaf(wc, v[j].x, a.x);
                    a.y = fmaf(wc, v[j].y, a.y);
                    a.z = fmaf(wc, v[j].z, a.z);
                    a.w = fmaf(wc, v[j].w, a.w);
                }
                out4[cbase + (unsigned)i * HW4 + p] = a;
            }
        }

#pragma unroll
        for (int j = 0; j < GS; ++j) v[j] = w[j];
        p = pn;
    }

    // final chunk
#pragma unroll
    for (int j = 0; j < GS; ++j) {
        v[j].x -= mv[j]; v[j].y -= mv[j]; v[j].z -= mv[j]; v[j].w -= mv[j];
    }
    if (p < pend) {
#pragma unroll
        for (int i = 0; i < GS; ++i) {
            float4 a;
            a.x = wv[tidx(i, 0)] * v[0].x;
            a.y = wv[tidx(i, 0)] * v[0].y;
            a.z = wv[tidx(i, 0)] * v[0].z;
            a.w = wv[tidx(i, 0)] * v[0].w;
#pragma unroll
            for (int j = 1; j <= i; ++j) {
                const float wc = wv[tidx(i, j)];
                a.x = fmaf(wc, v[j].x, a.x);
                a.y = fmaf(wc, v[j].y, a.y);
                a.z = fmaf(wc, v[j].z, a.z);
                a.w = fmaf(wc, v[j].w, a.w);
            }
            out4[cbase + (unsigned)i * HW4 + p] = a;
        }
    }
}

extern "C" void kernel_launch(void* const* d_in, const int* in_sizes, int n_in,
                              void* d_out, int out_size, void* d_ws, size_t ws_size,
                              hipStream_t stream) {
    const float* x = (const float*)d_in[0];
    float* out = (float*)d_out;

    float* ws = (float*)d_ws;
    float* sums = ws;                   // 256 floats
    float* gram = ws + 256;             // 16*136 = 2176 floats
    float* wmat = ws + 256 + 2176;      // 2176 floats (packed W per group)
    float* muv  = wmat + 2176;          // 256 floats

    // accumulators must start at zero (ws is poisoned each call)
    hipMemsetAsync(ws, 0, (256 + 2176) * sizeof(float), stream);

    dim3 grid(M_BATCH, NGROUPS, SPLIT);
    whiten_stats<<<grid, 64, 0, stream>>>((const float4*)x, sums, gram);
    whiten_solve<<<1, 64, 0, stream>>>(sums, gram, wmat, muv);
    whiten_apply<<<grid, 64, 0, stream>>>((const float4*)x, wmat, muv, (float4*)out);
}

// Round 2
// 267.697 us; speedup vs baseline: 1.4031x; 1.0920x over previous
//
#include <hip/hip_runtime.h>

// Problem constants (from reference): x = (32, 256, 56, 56) fp32
#define M_BATCH 32
#define D_FEAT 256
#define HW 3136              // 56*56
#define HW4 784              // HW/4, float4 elements per channel
#define NGROUPS 16
#define GS 16
#define NTOT (M_BATCH * HW)  // 100352 samples per channel
#define TRI 136              // 16*17/2 packed lower triangle
#define EPS_W 1e-6f

#define SPLIT 2
#define SLICE4 (HW4 / SPLIT)                 // 392 float4 per slice
#define CHUNK 64                             // float4 positions staged per iter
#define NIT ((SLICE4 + CHUNK - 1) / CHUNK)   // 7 (6 full + tail of 8)

__device__ __host__ constexpr int tidx(int i, int j) { return i * (i + 1) / 2 + j; }

__device__ __forceinline__ void wave_red_atomic(float v, int lane, float* addr) {
#pragma unroll
    for (int off = 32; off > 0; off >>= 1) v += __shfl_down(v, off, 64);
    if (lane == 0) atomicAdd(addr, v);
}

// ---------------------------------------------------------------------------
// Pass 1: per-channel sums + per-group packed Gram.
// Block = 256 thr (4 waves) per (b,g,slice). Tile of 16ch x 64 float4 staged
// in LDS (double-buffered, 32KB). Wave w owns balanced row set
// {w, 15-w, w+4, 11-w} = 34 cells (template params -> all reg indices static).
// Raw s_barrier + lgkmcnt-only wait so next-chunk global loads stay in flight
// across the barrier (T14 issue-early / write-late).
// ---------------------------------------------------------------------------
template <int R0, int R1, int R2, int R3>
__device__ __forceinline__ void stats_wave(const float4* __restrict__ x4,
                                           float* __restrict__ sums,
                                           float* __restrict__ gram,
                                           float4* tile, int g, unsigned cbase,
                                           unsigned pbase0, int w, int lane, int tid) {
    float a0[R0 + 1], a1[R1 + 1], a2[R2 + 1], a3[R3 + 1];
#pragma unroll
    for (int j = 0; j <= R0; ++j) a0[j] = 0.0f;
#pragma unroll
    for (int j = 0; j <= R1; ++j) a1[j] = 0.0f;
#pragma unroll
    for (int j = 0; j <= R2; ++j) a2[j] = 0.0f;
#pragma unroll
    for (int j = 0; j <= R3; ++j) a3[j] = 0.0f;
    float sv0 = 0.0f, sv1 = 0.0f, sv2 = 0.0f, sv3 = 0.0f;

    const float4 z4 = make_float4(0.0f, 0.0f, 0.0f, 0.0f);
    const unsigned pend = pbase0 + SLICE4;
    float4 r0, r1, r2, r3;
    {   // prologue: chunk 0 (staged channels for wave w: w, w+4, w+8, w+12)
        const unsigned base = pbase0;
        const unsigned go = cbase + base + lane;
        if (base + lane < pend) {
            r0 = x4[go + (unsigned)(w) * HW4];
            r1 = x4[go + (unsigned)(w + 4) * HW4];
            r2 = x4[go + (unsigned)(w + 8) * HW4];
            r3 = x4[go + (unsigned)(w + 12) * HW4];
        } else { r0 = r1 = r2 = r3 = z4; }
    }

    int cur = 0;
#pragma unroll 1
    for (int it = 0; it < NIT; ++it) {
        float4* tb = tile + cur * (16 * CHUNK);
        tb[tid] = r0;
        tb[tid + 256] = r1;
        tb[tid + 512] = r2;
        tb[tid + 768] = r3;
        if (it + 1 < NIT) {  // issue next-chunk loads; they fly through compute
            const unsigned base = pbase0 + (unsigned)(it + 1) * CHUNK;
            const unsigned go = cbase + base + lane;
            if (base + lane < pend) {
                r0 = x4[go + (unsigned)(w) * HW4];
                r1 = x4[go + (unsigned)(w + 4) * HW4];
                r2 = x4[go + (unsigned)(w + 8) * HW4];
                r3 = x4[go + (unsigned)(w + 12) * HW4];
            } else { r0 = r1 = r2 = r3 = z4; }
        }
        asm volatile("s_waitcnt lgkmcnt(0)" ::: "memory");  // ds_writes visible; vmcnt NOT drained
        __builtin_amdgcn_s_barrier();
        __builtin_amdgcn_sched_barrier(0);

        const float4* tl = tile + cur * (16 * CHUNK);
        float4 v0 = tl[R0 * CHUNK + lane];
        float4 v1 = tl[R1 * CHUNK + lane];
        float4 v2 = tl[R2 * CHUNK + lane];
        float4 v3 = tl[R3 * CHUNK + lane];
        sv0 += (v0.x + v0.y) + (v0.z + v0.w);
        sv1 += (v1.x + v1.y) + (v1.z + v1.w);
        sv2 += (v2.x + v2.y) + (v2.z + v2.w);
        sv3 += (v3.x + v3.y) + (v3.z + v3.w);
#pragma unroll
        for (int j = 0; j < GS; ++j) {
            float4 vj = tl[j * CHUNK + lane];
            if (j <= R0) { float t = a0[j]; t = fmaf(v0.x, vj.x, t); t = fmaf(v0.y, vj.y, t); t = fmaf(v0.z, vj.z, t); t = fmaf(v0.w, vj.w, t); a0[j] = t; }
            if (j <= R1) { float t = a1[j]; t = fmaf(v1.x, vj.x, t); t = fmaf(v1.y, vj.y, t); t = fmaf(v1.z, vj.z, t); t = fmaf(v1.w, vj.w, t); a1[j] = t; }
            if (j <= R2) { float t = a2[j]; t = fmaf(v2.x, vj.x, t); t = fmaf(v2.y, vj.y, t); t = fmaf(v2.z, vj.z, t); t = fmaf(v2.w, vj.w, t); a2[j] = t; }
            if (j <= R3) { float t = a3[j]; t = fmaf(v3.x, vj.x, t); t = fmaf(v3.y, vj.y, t); t = fmaf(v3.z, vj.z, t); t = fmaf(v3.w, vj.w, t); a3[j] = t; }
        }
        cur ^= 1;
    }

    wave_red_atomic(sv0, lane, &sums[g * GS + R0]);
    wave_red_atomic(sv1, lane, &sums[g * GS + R1]);
    wave_red_atomic(sv2, lane, &sums[g * GS + R2]);
    wave_red_atomic(sv3, lane, &sums[g * GS + R3]);
#pragma unroll
    for (int j = 0; j <= R0; ++j) wave_red_atomic(a0[j], lane, &gram[g * TRI + tidx(R0, j)]);
#pragma unroll
    for (int j = 0; j <= R1; ++j) wave_red_atomic(a1[j], lane, &gram[g * TRI + tidx(R1, j)]);
#pragma unroll
    for (int j = 0; j <= R2; ++j) wave_red_atomic(a2[j], lane, &gram[g * TRI + tidx(R2, j)]);
#pragma unroll
    for (int j = 0; j <= R3; ++j) wave_red_atomic(a3[j], lane, &gram[g * TRI + tidx(R3, j)]);
}

__global__ __launch_bounds__(256, 4) void whiten_stats(const float4* __restrict__ x4,
                                                       float* __restrict__ sums,
                                                       float* __restrict__ gram) {
    __shared__ float4 tile[2 * 16 * CHUNK];  // 32 KB
    const int tid = threadIdx.x, w = tid >> 6, lane = tid & 63;
    const int g = blockIdx.y;
    const unsigned cbase = ((unsigned)blockIdx.x * D_FEAT + (unsigned)g * GS) * HW4;
    const unsigned pbase0 = (unsigned)blockIdx.z * SLICE4;
    switch (w) {
        case 0: stats_wave<0, 15, 4, 11>(x4, sums, gram, tile, g, cbase, pbase0, 0, lane, tid); break;
        case 1: stats_wave<1, 14, 5, 10>(x4, sums, gram, tile, g, cbase, pbase0, 1, lane, tid); break;
        case 2: stats_wave<2, 13, 6, 9>(x4, sums, gram, tile, g, cbase, pbase0, 2, lane, tid); break;
        default: stats_wave<3, 12, 7, 8>(x4, sums, gram, tile, g, cbase, pbase0, 3, lane, tid); break;
    }
}

// ---------------------------------------------------------------------------
// Pass 2: sigma -> Cholesky -> inv(T). Unchanged (tiny, one wave).
// ---------------------------------------------------------------------------
__global__ __launch_bounds__(64, 1) void whiten_solve(const float* __restrict__ sums,
                                                      const float* __restrict__ gram,
                                                      float* __restrict__ wout,
                                                      float* __restrict__ muout) {
    const int g = threadIdx.x;
    if (g >= NGROUPS) return;

    float mu[GS];
#pragma unroll
    for (int j = 0; j < GS; ++j) mu[j] = sums[g * GS + j] * (1.0f / (float)NTOT);

    float S[TRI];
#pragma unroll
    for (int i = 0; i < GS; ++i) {
#pragma unroll
        for (int j = 0; j <= i; ++j) {
            float sg = (gram[g * TRI + tidx(i, j)] - (float)NTOT * mu[i] * mu[j])
                       * (1.0f / (float)(NTOT - 1));
            sg *= (1.0f - EPS_W);
            if (i == j) sg += EPS_W;
            S[tidx(i, j)] = sg;
        }
    }

#pragma unroll
    for (int c = 0; c < GS; ++c) {
        float d = S[tidx(c, c)];
#pragma unroll
        for (int k = 0; k < c; ++k) d -= S[tidx(c, k)] * S[tidx(c, k)];
        d = sqrtf(d);
        S[tidx(c, c)] = d;
        const float inv = 1.0f / d;
#pragma unroll
        for (int i = c + 1; i < GS; ++i) {
            float t = S[tidx(i, c)];
#pragma unroll
            for (int k = 0; k < c; ++k) t -= S[tidx(i, k)] * S[tidx(c, k)];
            S[tidx(i, c)] = t * inv;
        }
    }

#pragma unroll
    for (int c = 0; c < GS; ++c) {
        const float wcc = 1.0f / S[tidx(c, c)];
        S[tidx(c, c)] = wcc;
#pragma unroll
        for (int i = c + 1; i < GS; ++i) {
            float a = 0.0f;
#pragma unroll
            for (int k = c; k < i; ++k) a += S[tidx(i, k)] * S[tidx(k, c)];
            S[tidx(i, c)] = -a / S[tidx(i, i)];
        }
    }

#pragma unroll
    for (int k = 0; k < TRI; ++k) wout[g * TRI + k] = S[k];
#pragma unroll
    for (int j = 0; j < GS; ++j) muout[g * GS + j] = mu[j];
}

// ---------------------------------------------------------------------------
// Pass 3: out = W*(x-mu). Same 4-wave LDS-tile scheme; wave w owns output rows
// {w,15-w,w+4,11-w} (34 coeffs); mean folded into per-row constant c_r.
// ---------------------------------------------------------------------------
template <int R0, int R1, int R2, int R3>
__device__ __forceinline__ void apply_wave(const float4* __restrict__ x4,
                                           const float* __restrict__ wmat,
                                           const float* __restrict__ muv,
                                           float4* __restrict__ out4, float4* tile,
                                           int g, unsigned cbase, unsigned pbase0,
                                           int w, int lane, int tid) {
    float w0[R0 + 1], w1[R1 + 1], w2[R2 + 1], w3[R3 + 1];
    float c0 = 0.0f, c1 = 0.0f, c2 = 0.0f, c3 = 0.0f;
#pragma unroll
    for (int j = 0; j <= R0; ++j) { w0[j] = wmat[g * TRI + tidx(R0, j)]; c0 = fmaf(w0[j], muv[g * GS + j], c0); }
#pragma unroll
    for (int j = 0; j <= R1; ++j) { w1[j] = wmat[g * TRI + tidx(R1, j)]; c1 = fmaf(w1[j], muv[g * GS + j], c1); }
#pragma unroll
    for (int j = 0; j <= R2; ++j) { w2[j] = wmat[g * TRI + tidx(R2, j)]; c2 = fmaf(w2[j], muv[g * GS + j], c2); }
#pragma unroll
    for (int j = 0; j <= R3; ++j) { w3[j] = wmat[g * TRI + tidx(R3, j)]; c3 = fmaf(w3[j], muv[g * GS + j], c3); }

    const float4 z4 = make_float4(0.0f, 0.0f, 0.0f, 0.0f);
    const unsigned pend = pbase0 + SLICE4;
    float4 r0, r1, r2, r3;
    {
        const unsigned base = pbase0;
        const unsigned go = cbase + base + lane;
        if (base + lane < pend) {
            r0 = x4[go + (unsigned)(w) * HW4];
            r1 = x4[go + (unsigned)(w + 4) * HW4];
            r2 = x4[go + (unsigned)(w + 8) * HW4];
            r3 = x4[go + (unsigned)(w + 12) * HW4];
        } else { r0 = r1 = r2 = r3 = z4; }
    }

    int cur = 0;
#pragma unroll 1
    for (int it = 0; it < NIT; ++it) {
        float4* tb = tile + cur * (16 * CHUNK);
        tb[tid] = r0;
        tb[tid + 256] = r1;
        tb[tid + 512] = r2;
        tb[tid + 768] = r3;
        if (it + 1 < NIT) {
            const unsigned base = pbase0 + (unsigned)(it + 1) * CHUNK;
            const unsigned go = cbase + base + lane;
            if (base + lane < pend) {
                r0 = x4[go + (unsigned)(w) * HW4];
                r1 = x4[go + (unsigned)(w + 4) * HW4];
                r2 = x4[go + (unsigned)(w + 8) * HW4];
                r3 = x4[go + (unsigned)(w + 12) * HW4];
            } else { r0 = r1 = r2 = r3 = z4; }
        }
        asm volatile("s_waitcnt lgkmcnt(0)" ::: "memory");
        __builtin_amdgcn_s_barrier();
        __builtin_amdgcn_sched_barrier(0);

        const float4* tl = tile + cur * (16 * CHUNK);
        float4 o0, o1, o2, o3;
        o0.x = o0.y = o0.z = o0.w = -c0;
        o1.x = o1.y = o1.z = o1.w = -c1;
        o2.x = o2.y = o2.z = o2.w = -c2;
        o3.x = o3.y = o3.z = o3.w = -c3;
#pragma unroll
        for (int j = 0; j < GS; ++j) {
            float4 vj = tl[j * CHUNK + lane];
            if (j <= R0) { o0.x = fmaf(w0[j], vj.x, o0.x); o0.y = fmaf(w0[j], vj.y, o0.y); o0.z = fmaf(w0[j], vj.z, o0.z); o0.w = fmaf(w0[j], vj.w, o0.w); }
            if (j <= R1) { o1.x = fmaf(w1[j], vj.x, o1.x); o1.y = fmaf(w1[j], vj.y, o1.y); o1.z = fmaf(w1[j], vj.z, o1.z); o1.w = fmaf(w1[j], vj.w, o1.w); }
            if (j <= R2) { o2.x = fmaf(w2[j], vj.x, o2.x); o2.y = fmaf(w2[j], vj.y, o2.y); o2.z = fmaf(w2[j], vj.z, o2.z); o2.w = fmaf(w2[j], vj.w, o2.w); }
            if (j <= R3) { o3.x = fmaf(w3[j], vj.x, o3.x); o3.y = fmaf(w3[j], vj.y, o3.y); o3.z = fmaf(w3[j], vj.z, o3.z); o3.w = fmaf(w3[j], vj.w, o3.w); }
        }
        const unsigned basec = pbase0 + (unsigned)it * CHUNK;
        if (basec + lane < pend) {
            const unsigned go = cbase + basec + lane;
            out4[go + (unsigned)R0 * HW4] = o0;
            out4[go + (unsigned)R1 * HW4] = o1;
            out4[go + (unsigned)R2 * HW4] = o2;
            out4[go + (unsigned)R3 * HW4] = o3;
        }
        cur ^= 1;
    }
}

__global__ __launch_bounds__(256, 4) void whiten_apply(const float4* __restrict__ x4,
                                                       const float* __restrict__ wmat,
                                                       const float* __restrict__ muv,
                                                       float4* __restrict__ out4) {
    __shared__ float4 tile[2 * 16 * CHUNK];  // 32 KB
    const int tid = threadIdx.x, w = tid >> 6, lane = tid & 63;
    const int g = blockIdx.y;
    const unsigned cbase = ((unsigned)blockIdx.x * D_FEAT + (unsigned)g * GS) * HW4;
    const unsigned pbase0 = (unsigned)blockIdx.z * SLICE4;
    switch (w) {
        case 0: apply_wave<0, 15, 4, 11>(x4, wmat, muv, out4, tile, g, cbase, pbase0, 0, lane, tid); break;
        case 1: apply_wave<1, 14, 5, 10>(x4, wmat, muv, out4, tile, g, cbase, pbase0, 1, lane, tid); break;
        case 2: apply_wave<2, 13, 6, 9>(x4, wmat, muv, out4, tile, g, cbase, pbase0, 2, lane, tid); break;
        default: apply_wave<3, 12, 7, 8>(x4, wmat, muv, out4, tile, g, cbase, pbase0, 3, lane, tid); break;
    }
}

extern "C" void kernel_launch(void* const* d_in, const int* in_sizes, int n_in,
                              void* d_out, int out_size, void* d_ws, size_t ws_size,
                              hipStream_t stream) {
    const float* x = (const float*)d_in[0];
    float* out = (float*)d_out;

    float* ws = (float*)d_ws;
    float* sums = ws;                   // 256 floats
    float* gram = ws + 256;             // 16*136 = 2176 floats
    float* wmat = ws + 256 + 2176;      // 2176 floats (packed W per group)
    float* muv  = wmat + 2176;          // 256 floats

    hipMemsetAsync(ws, 0, (256 + 2176) * sizeof(float), stream);

    dim3 grid(M_BATCH, NGROUPS, SPLIT);
    whiten_stats<<<grid, 256, 0, stream>>>((const float4*)x, sums, gram);
    whiten_solve<<<1, 64, 0, stream>>>(sums, gram, wmat, muv);
    whiten_apply<<<grid, 256, 0, stream>>>((const float4*)x, wmat, muv, (float4*)out);
}

// Round 3
// 251.466 us; speedup vs baseline: 1.4937x; 1.0645x over previous
//
#include <hip/hip_runtime.h>

// Problem constants (from reference): x = (32, 256, 56, 56) fp32
#define M_BATCH 32
#define D_FEAT 256
#define HW 3136              // 56*56
#define HW4 784              // HW/4, float4 elements per channel
#define NGROUPS 16
#define GS 16
#define NTOT (M_BATCH * HW)  // 100352 samples per channel
#define TRI 136              // 16*17/2 packed lower triangle
#define EPS_W 1e-6f

#define SPLIT 2
#define SLICE4 (HW4 / SPLIT)           // 392 float4 per slice
#define CHUNK 64                       // float4 positions per staged chunk
#define NFULL (SLICE4 / CHUNK)         // 6 full chunks
#define TAIL4 (SLICE4 - NFULL * CHUNK) // 8 tail positions
#define BUFSZ (GS * CHUNK)             // 1024 float4 per LDS buffer

__device__ __host__ constexpr int tidx(int i, int j) { return i * (i + 1) / 2 + j; }

// async global->LDS, 16B per lane. LDS dest = wave-uniform base + lane*16
// (linear layout tile[ch*CHUNK + lane] matches exactly).
__device__ __forceinline__ void async16(const float4* g, float4* l) {
    __builtin_amdgcn_global_load_lds(
        (const __attribute__((address_space(1))) void*)g,
        (__attribute__((address_space(3))) void*)l, 16, 0, 0);
}

__device__ __forceinline__ void wave_red_atomic(float v, int lane, float* addr) {
#pragma unroll
    for (int off = 32; off > 0; off >>= 1) v += __shfl_down(v, off, 64);
    if (lane == 0) atomicAdd(addr, v);
}

// Gram accumulate for this wave's 4 rows from an LDS tile with row stride STRIDE.
#define ACCUM_BLOCK(TL, STRIDE)                                                                                   \
    {                                                                                                             \
        const float4 v0 = (TL)[R0 * (STRIDE) + lane];                                                             \
        const float4 v1 = (TL)[R1 * (STRIDE) + lane];                                                             \
        const float4 v2 = (TL)[R2 * (STRIDE) + lane];                                                             \
        const float4 v3 = (TL)[R3 * (STRIDE) + lane];                                                             \
        sv0 += (v0.x + v0.y) + (v0.z + v0.w);                                                                     \
        sv1 += (v1.x + v1.y) + (v1.z + v1.w);                                                                     \
        sv2 += (v2.x + v2.y) + (v2.z + v2.w);                                                                     \
        sv3 += (v3.x + v3.y) + (v3.z + v3.w);                                                                     \
        _Pragma("unroll") for (int j = 0; j < GS; ++j) {                                                          \
            const float4 vj = (TL)[j * (STRIDE) + lane];                                                          \
            if (j <= R0) { float t = a0[j]; t = fmaf(v0.x, vj.x, t); t = fmaf(v0.y, vj.y, t); t = fmaf(v0.z, vj.z, t); t = fmaf(v0.w, vj.w, t); a0[j] = t; } \
            if (j <= R1) { float t = a1[j]; t = fmaf(v1.x, vj.x, t); t = fmaf(v1.y, vj.y, t); t = fmaf(v1.z, vj.z, t); t = fmaf(v1.w, vj.w, t); a1[j] = t; } \
            if (j <= R2) { float t = a2[j]; t = fmaf(v2.x, vj.x, t); t = fmaf(v2.y, vj.y, t); t = fmaf(v2.z, vj.z, t); t = fmaf(v2.w, vj.w, t); a2[j] = t; } \
            if (j <= R3) { float t = a3[j]; t = fmaf(v3.x, vj.x, t); t = fmaf(v3.y, vj.y, t); t = fmaf(v3.z, vj.z, t); t = fmaf(v3.w, vj.w, t); a3[j] = t; } \
        }                                                                                                         \
    }

// ---------------------------------------------------------------------------
// Pass 1: per-channel sums + per-group packed Gram.
// Block = 4 waves per (b,g,slice); wave w owns rows {w,15-w,w+4,11-w} (34 cells)
// and stages channels {w,w+4,w+8,w+12} via global_load_lds (no staging VGPRs,
// no ds_writes). Counted vmcnt + raw s_barrier; next-chunk loads issued right
// after the barrier (other buffer provably idle) and overlap the FMA phase.
// ---------------------------------------------------------------------------
template <int R0, int R1, int R2, int R3>
__device__ __forceinline__ void stats_wave(const float4* __restrict__ x4,
                                           float* __restrict__ sums,
                                           float* __restrict__ gram,
                                           float4* tile, float4* tailb,
                                           int g, unsigned cbase, unsigned pbase0,
                                           int w, int lane) {
    float a0[R0 + 1], a1[R1 + 1], a2[R2 + 1], a3[R3 + 1];
#pragma unroll
    for (int j = 0; j <= R0; ++j) a0[j] = 0.0f;
#pragma unroll
    for (int j = 0; j <= R1; ++j) a1[j] = 0.0f;
#pragma unroll
    for (int j = 0; j <= R2; ++j) a2[j] = 0.0f;
#pragma unroll
    for (int j = 0; j <= R3; ++j) a3[j] = 0.0f;
    float sv0 = 0.0f, sv1 = 0.0f, sv2 = 0.0f, sv3 = 0.0f;

    {   // prologue: chunk 0 -> buffer 0
        const float4* gs = x4 + cbase + pbase0 + (unsigned)lane;
        async16(gs + (unsigned)(w) * HW4,      tile + (w) * CHUNK);
        async16(gs + (unsigned)(w + 4) * HW4,  tile + (w + 4) * CHUNK);
        async16(gs + (unsigned)(w + 8) * HW4,  tile + (w + 8) * CHUNK);
        async16(gs + (unsigned)(w + 12) * HW4, tile + (w + 12) * CHUNK);
    }

#pragma unroll 1
    for (int it = 0; it < NFULL; ++it) {
        asm volatile("s_waitcnt vmcnt(0)" ::: "memory");  // own chunk-it loads done
        __builtin_amdgcn_s_barrier();                     // everyone's done
        __builtin_amdgcn_sched_barrier(0);

        if (it + 1 < NFULL) {
            float4* nb = tile + (unsigned)((it + 1) & 1) * BUFSZ;
            const float4* gs = x4 + cbase + pbase0 + (unsigned)(it + 1) * CHUNK + (unsigned)lane;
            async16(gs + (unsigned)(w) * HW4,      nb + (w) * CHUNK);
            async16(gs + (unsigned)(w + 4) * HW4,  nb + (w + 4) * CHUNK);
            async16(gs + (unsigned)(w + 8) * HW4,  nb + (w + 8) * CHUNK);
            async16(gs + (unsigned)(w + 12) * HW4, nb + (w + 12) * CHUNK);
        } else if (lane < TAIL4) {  // tail chunk (8 positions) into dedicated region
            const float4* gs = x4 + cbase + pbase0 + (unsigned)(NFULL * CHUNK) + (unsigned)lane;
            async16(gs + (unsigned)(w) * HW4,      tailb + (w) * TAIL4);
            async16(gs + (unsigned)(w + 4) * HW4,  tailb + (w + 4) * TAIL4);
            async16(gs + (unsigned)(w + 8) * HW4,  tailb + (w + 8) * TAIL4);
            async16(gs + (unsigned)(w + 12) * HW4, tailb + (w + 12) * TAIL4);
        }

        const float4* tl = tile + (unsigned)(it & 1) * BUFSZ;
        ACCUM_BLOCK(tl, CHUNK)
    }

    // tail phase
    asm volatile("s_waitcnt vmcnt(0)" ::: "memory");
    __builtin_amdgcn_s_barrier();
    __builtin_amdgcn_sched_barrier(0);
    if (lane < TAIL4) {
        const float4* tl = tailb;
        ACCUM_BLOCK(tl, TAIL4)
    }

    wave_red_atomic(sv0, lane, &sums[g * GS + R0]);
    wave_red_atomic(sv1, lane, &sums[g * GS + R1]);
    wave_red_atomic(sv2, lane, &sums[g * GS + R2]);
    wave_red_atomic(sv3, lane, &sums[g * GS + R3]);
#pragma unroll
    for (int j = 0; j <= R0; ++j) wave_red_atomic(a0[j], lane, &gram[g * TRI + tidx(R0, j)]);
#pragma unroll
    for (int j = 0; j <= R1; ++j) wave_red_atomic(a1[j], lane, &gram[g * TRI + tidx(R1, j)]);
#pragma unroll
    for (int j = 0; j <= R2; ++j) wave_red_atomic(a2[j], lane, &gram[g * TRI + tidx(R2, j)]);
#pragma unroll
    for (int j = 0; j <= R3; ++j) wave_red_atomic(a3[j], lane, &gram[g * TRI + tidx(R3, j)]);
}

__global__ __launch_bounds__(256) __attribute__((amdgpu_waves_per_eu(4, 4)))
void whiten_stats(const float4* __restrict__ x4, float* __restrict__ sums,
                  float* __restrict__ gram) {
    __shared__ float4 tile[2 * BUFSZ + GS * TAIL4];  // 32KB dbuf + 2KB tail = 34KB
    const int tid = threadIdx.x, w = tid >> 6, lane = tid & 63;
    const int g = blockIdx.y;
    const unsigned cbase = ((unsigned)blockIdx.x * D_FEAT + (unsigned)g * GS) * HW4;
    const unsigned pbase0 = (unsigned)blockIdx.z * SLICE4;
    float4* tailb = tile + 2 * BUFSZ;
    switch (w) {
        case 0: stats_wave<0, 15, 4, 11>(x4, sums, gram, tile, tailb, g, cbase, pbase0, 0, lane); break;
        case 1: stats_wave<1, 14, 5, 10>(x4, sums, gram, tile, tailb, g, cbase, pbase0, 1, lane); break;
        case 2: stats_wave<2, 13, 6, 9>(x4, sums, gram, tile, tailb, g, cbase, pbase0, 2, lane); break;
        default: stats_wave<3, 12, 7, 8>(x4, sums, gram, tile, tailb, g, cbase, pbase0, 3, lane); break;
    }
}

// ---------------------------------------------------------------------------
// Pass 2: sigma -> Cholesky -> inv(T). Tiny, unchanged.
// ---------------------------------------------------------------------------
__global__ __launch_bounds__(64, 1) void whiten_solve(const float* __restrict__ sums,
                                                      const float* __restrict__ gram,
                                                      float* __restrict__ wout,
                                                      float* __restrict__ muout) {
    const int g = threadIdx.x;
    if (g >= NGROUPS) return;

    float mu[GS];
#pragma unroll
    for (int j = 0; j < GS; ++j) mu[j] = sums[g * GS + j] * (1.0f / (float)NTOT);

    float S[TRI];
#pragma unroll
    for (int i = 0; i < GS; ++i) {
#pragma unroll
        for (int j = 0; j <= i; ++j) {
            float sg = (gram[g * TRI + tidx(i, j)] - (float)NTOT * mu[i] * mu[j])
                       * (1.0f / (float)(NTOT - 1));
            sg *= (1.0f - EPS_W);
            if (i == j) sg += EPS_W;
            S[tidx(i, j)] = sg;
        }
    }

#pragma unroll
    for (int c = 0; c < GS; ++c) {
        float d = S[tidx(c, c)];
#pragma unroll
        for (int k = 0; k < c; ++k) d -= S[tidx(c, k)] * S[tidx(c, k)];
        d = sqrtf(d);
        S[tidx(c, c)] = d;
        const float inv = 1.0f / d;
#pragma unroll
        for (int i = c + 1; i < GS; ++i) {
            float t = S[tidx(i, c)];
#pragma unroll
            for (int k = 0; k < c; ++k) t -= S[tidx(i, k)] * S[tidx(c, k)];
            S[tidx(i, c)] = t * inv;
        }
    }

#pragma unroll
    for (int c = 0; c < GS; ++c) {
        const float wcc = 1.0f / S[tidx(c, c)];
        S[tidx(c, c)] = wcc;
#pragma unroll
        for (int i = c + 1; i < GS; ++i) {
            float a = 0.0f;
#pragma unroll
            for (int k = c; k < i; ++k) a += S[tidx(i, k)] * S[tidx(k, c)];
            S[tidx(i, c)] = -a / S[tidx(i, i)];
        }
    }

#pragma unroll
    for (int k = 0; k < TRI; ++k) wout[g * TRI + k] = S[k];
#pragma unroll
    for (int j = 0; j < GS; ++j) muout[g * GS + j] = mu[j];
}

// ---------------------------------------------------------------------------
// Pass 3: out = W*(x-mu). Same async-staging scheme; wave w owns output rows
// {w,15-w,w+4,11-w}; mean folded into per-row constant. vmcnt(4) keeps the
// previous iteration's 4 stores in flight while waiting only on the loads.
// ---------------------------------------------------------------------------
#define APPLY_BLOCK(TL, STRIDE)                                                                   \
    float4 o0, o1, o2, o3;                                                                        \
    o0.x = o0.y = o0.z = o0.w = -c0;                                                              \
    o1.x = o1.y = o1.z = o1.w = -c1;                                                              \
    o2.x = o2.y = o2.z = o2.w = -c2;                                                              \
    o3.x = o3.y = o3.z = o3.w = -c3;                                                              \
    _Pragma("unroll") for (int j = 0; j < GS; ++j) {                                              \
        const float4 vj = (TL)[j * (STRIDE) + lane];                                              \
        if (j <= R0) { o0.x = fmaf(w0[j], vj.x, o0.x); o0.y = fmaf(w0[j], vj.y, o0.y); o0.z = fmaf(w0[j], vj.z, o0.z); o0.w = fmaf(w0[j], vj.w, o0.w); } \
        if (j <= R1) { o1.x = fmaf(w1[j], vj.x, o1.x); o1.y = fmaf(w1[j], vj.y, o1.y); o1.z = fmaf(w1[j], vj.z, o1.z); o1.w = fmaf(w1[j], vj.w, o1.w); } \
        if (j <= R2) { o2.x = fmaf(w2[j], vj.x, o2.x); o2.y = fmaf(w2[j], vj.y, o2.y); o2.z = fmaf(w2[j], vj.z, o2.z); o2.w = fmaf(w2[j], vj.w, o2.w); } \
        if (j <= R3) { o3.x = fmaf(w3[j], vj.x, o3.x); o3.y = fmaf(w3[j], vj.y, o3.y); o3.z = fmaf(w3[j], vj.z, o3.z); o3.w = fmaf(w3[j], vj.w, o3.w); } \
    }

template <int R0, int R1, int R2, int R3>
__device__ __forceinline__ void apply_wave(const float4* __restrict__ x4,
                                           const float* __restrict__ wmat,
                                           const float* __restrict__ muv,
                                           float4* __restrict__ out4,
                                           float4* tile, float4* tailb,
                                           int g, unsigned cbase, unsigned pbase0,
                                           int w, int lane) {
    float w0[R0 + 1], w1[R1 + 1], w2[R2 + 1], w3[R3 + 1];
    float c0 = 0.0f, c1 = 0.0f, c2 = 0.0f, c3 = 0.0f;
#pragma unroll
    for (int j = 0; j <= R0; ++j) { w0[j] = wmat[g * TRI + tidx(R0, j)]; c0 = fmaf(w0[j], muv[g * GS + j], c0); }
#pragma unroll
    for (int j = 0; j <= R1; ++j) { w1[j] = wmat[g * TRI + tidx(R1, j)]; c1 = fmaf(w1[j], muv[g * GS + j], c1); }
#pragma unroll
    for (int j = 0; j <= R2; ++j) { w2[j] = wmat[g * TRI + tidx(R2, j)]; c2 = fmaf(w2[j], muv[g * GS + j], c2); }
#pragma unroll
    for (int j = 0; j <= R3; ++j) { w3[j] = wmat[g * TRI + tidx(R3, j)]; c3 = fmaf(w3[j], muv[g * GS + j], c3); }

    {   // prologue: chunk 0 -> buffer 0
        const float4* gs = x4 + cbase + pbase0 + (unsigned)lane;
        async16(gs + (unsigned)(w) * HW4,      tile + (w) * CHUNK);
        async16(gs + (unsigned)(w + 4) * HW4,  tile + (w + 4) * CHUNK);
        async16(gs + (unsigned)(w + 8) * HW4,  tile + (w + 8) * CHUNK);
        async16(gs + (unsigned)(w + 12) * HW4, tile + (w + 12) * CHUNK);
    }

#pragma unroll 1
    for (int it = 0; it < NFULL; ++it) {
        // iter 0: only the 4 prologue loads outstanding. later: 4 loads (oldest)
        // + 4 stores (newest) -> vmcnt(4) retires exactly the loads (FIFO).
        if (it == 0) { asm volatile("s_waitcnt vmcnt(0)" ::: "memory"); }
        else         { asm volatile("s_waitcnt vmcnt(4)" ::: "memory"); }
        __builtin_amdgcn_s_barrier();
        __builtin_amdgcn_sched_barrier(0);

        if (it + 1 < NFULL) {
            float4* nb = tile + (unsigned)((it + 1) & 1) * BUFSZ;
            const float4* gs = x4 + cbase + pbase0 + (unsigned)(it + 1) * CHUNK + (unsigned)lane;
            async16(gs + (unsigned)(w) * HW4,      nb + (w) * CHUNK);
            async16(gs + (unsigned)(w + 4) * HW4,  nb + (w + 4) * CHUNK);
            async16(gs + (unsigned)(w + 8) * HW4,  nb + (w + 8) * CHUNK);
            async16(gs + (unsigned)(w + 12) * HW4, nb + (w + 12) * CHUNK);
        } else if (lane < TAIL4) {
            const float4* gs = x4 + cbase + pbase0 + (unsigned)(NFULL * CHUNK) + (unsigned)lane;
            async16(gs + (unsigned)(w) * HW4,      tailb + (w) * TAIL4);
            async16(gs + (unsigned)(w + 4) * HW4,  tailb + (w + 4) * TAIL4);
            async16(gs + (unsigned)(w + 8) * HW4,  tailb + (w + 8) * TAIL4);
            async16(gs + (unsigned)(w + 12) * HW4, tailb + (w + 12) * TAIL4);
        }

        const float4* tl = tile + (unsigned)(it & 1) * BUFSZ;
        APPLY_BLOCK(tl, CHUNK)
        const unsigned go = cbase + pbase0 + (unsigned)it * CHUNK + (unsigned)lane;
        out4[go + (unsigned)R0 * HW4] = o0;
        out4[go + (unsigned)R1 * HW4] = o1;
        out4[go + (unsigned)R2 * HW4] = o2;
        out4[go + (unsigned)R3 * HW4] = o3;
    }

    // tail phase (loads are oldest among outstanding; vmcnt(4) leaves last stores)
    asm volatile("s_waitcnt vmcnt(4)" ::: "memory");
    __builtin_amdgcn_s_barrier();
    __builtin_amdgcn_sched_barrier(0);
    if (lane < TAIL4) {
        const float4* tl = tailb;
        APPLY_BLOCK(tl, TAIL4)
        const unsigned go = cbase + pbase0 + (unsigned)(NFULL * CHUNK) + (unsigned)lane;
        out4[go + (unsigned)R0 * HW4] = o0;
        out4[go + (unsigned)R1 * HW4] = o1;
        out4[go + (unsigned)R2 * HW4] = o2;
        out4[go + (unsigned)R3 * HW4] = o3;
    }
}

__global__ __launch_bounds__(256) __attribute__((amdgpu_waves_per_eu(4, 4)))
void whiten_apply(const float4* __restrict__ x4, const float* __restrict__ wmat,
                  const float* __restrict__ muv, float4* __restrict__ out4) {
    __shared__ float4 tile[2 * BUFSZ + GS * TAIL4];  // 34KB
    const int tid = threadIdx.x, w = tid >> 6, lane = tid & 63;
    const int g = blockIdx.y;
    const unsigned cbase = ((unsigned)blockIdx.x * D_FEAT + (unsigned)g * GS) * HW4;
    const unsigned pbase0 = (unsigned)blockIdx.z * SLICE4;
    float4* tailb = tile + 2 * BUFSZ;
    switch (w) {
        case 0: apply_wave<0, 15, 4, 11>(x4, wmat, muv, out4, tile, tailb, g, cbase, pbase0, 0, lane); break;
        case 1: apply_wave<1, 14, 5, 10>(x4, wmat, muv, out4, tile, tailb, g, cbase, pbase0, 1, lane); break;
        case 2: apply_wave<2, 13, 6, 9>(x4, wmat, muv, out4, tile, tailb, g, cbase, pbase0, 2, lane); break;
        default: apply_wave<3, 12, 7, 8>(x4, wmat, muv, out4, tile, tailb, g, cbase, pbase0, 3, lane); break;
    }
}

extern "C" void kernel_launch(void* const* d_in, const int* in_sizes, int n_in,
                              void* d_out, int out_size, void* d_ws, size_t ws_size,
                              hipStream_t stream) {
    const float* x = (const float*)d_in[0];
    float* out = (float*)d_out;

    float* ws = (float*)d_ws;
    float* sums = ws;                   // 256 floats
    float* gram = ws + 256;             // 2176 floats
    float* wmat = ws + 256 + 2176;      // 2176 floats
    float* muv  = wmat + 2176;          // 256 floats

    hipMemsetAsync(ws, 0, (256 + 2176) * sizeof(float), stream);

    dim3 grid(M_BATCH, NGROUPS, SPLIT);
    whiten_stats<<<grid, 256, 0, stream>>>((const float4*)x, sums, gram);
    whiten_solve<<<1, 64, 0, stream>>>(sums, gram, wmat, muv);
    whiten_apply<<<grid, 256, 0, stream>>>((const float4*)x, wmat, muv, (float4*)out);
}

// Round 4
// 250.715 us; speedup vs baseline: 1.4982x; 1.0030x over previous
//
#include <hip/hip_runtime.h>

// Problem constants (from reference): x = (32, 256, 56, 56) fp32
#define M_BATCH 32
#define D_FEAT 256
#define HW 3136              // 56*56
#define HW2 1568             // float2 elements per channel
#define NGROUPS 16
#define GS 16
#define NTOT (M_BATCH * HW)  // 100352 samples per channel
#define TRI 136              // 16*17/2 packed lower triangle
#define EPS_W 1e-6f

__device__ __host__ constexpr int tidx(int i, int j) { return i * (i + 1) / 2 + j; }

// ---------------------------------------------------------------------------
// Pass 1: per-channel sums + per-group packed Gram.
// PURE-TLP streaming: no LDS staging, no barriers in the hot loop. Each thread
// grid-strides positions (float2), keeps all 16 channel values + all 136
// accumulators in registers. launch_bounds(256,2) -> 256-VGPR budget, 8
// independent waves/CU each with 16 outstanding 512B loads (~64KB/CU in
// flight) -> latency hidden by TLP, not by barrier-coupled prefetch (which
// plateaued at ~1.3 B/clk/block in rounds 1-3).
// ---------------------------------------------------------------------------
__global__ __launch_bounds__(256, 2) void whiten_stats(const float2* __restrict__ x2,
                                                       float* __restrict__ sums,
                                                       float* __restrict__ gram) {
    const int b = blockIdx.x, g = blockIdx.y;
    const int tid = threadIdx.x, w = tid >> 6, lane = tid & 63;
    const float2* base = x2 + ((size_t)b * D_FEAT + (size_t)g * GS) * HW2;

    float acc[TRI], sv[GS];
#pragma unroll
    for (int k = 0; k < TRI; ++k) acc[k] = 0.0f;
#pragma unroll
    for (int j = 0; j < GS; ++j) sv[j] = 0.0f;

#pragma unroll 1
    for (int p = tid; p < HW2; p += 256) {
        float2 v[GS];
#pragma unroll
        for (int j = 0; j < GS; ++j) v[j] = base[(size_t)j * HW2 + p];
#pragma unroll
        for (int i = 0; i < GS; ++i) {
            sv[i] += v[i].x + v[i].y;
#pragma unroll
            for (int j = 0; j <= i; ++j) {
                float t = acc[tidx(i, j)];
                t = fmaf(v[i].x, v[j].x, t);
                t = fmaf(v[i].y, v[j].y, t);
                acc[tidx(i, j)] = t;
            }
        }
    }

    // Epilogue: wave shuffle-reduce -> per-wave LDS slot -> 4-way sum ->
    // one atomic per cell per block (32 blocks/cell contention: negligible).
    __shared__ float red[4][TRI + GS];
#pragma unroll
    for (int k = 0; k < TRI; ++k) {
        float r = acc[k];
#pragma unroll
        for (int off = 32; off > 0; off >>= 1) r += __shfl_down(r, off, 64);
        if (lane == 0) red[w][k] = r;
    }
#pragma unroll
    for (int j = 0; j < GS; ++j) {
        float r = sv[j];
#pragma unroll
        for (int off = 32; off > 0; off >>= 1) r += __shfl_down(r, off, 64);
        if (lane == 0) red[w][TRI + j] = r;
    }
    __syncthreads();
    if (tid < TRI) {
        atomicAdd(&gram[g * TRI + tid],
                  red[0][tid] + red[1][tid] + red[2][tid] + red[3][tid]);
    } else if (tid < TRI + GS) {
        atomicAdd(&sums[g * GS + (tid - TRI)],
                  red[0][tid] + red[1][tid] + red[2][tid] + red[3][tid]);
    }
}

// ---------------------------------------------------------------------------
// Pass 2: sigma -> Cholesky -> inv(T). Tiny, unchanged.
// ---------------------------------------------------------------------------
__global__ __launch_bounds__(64, 1) void whiten_solve(const float* __restrict__ sums,
                                                      const float* __restrict__ gram,
                                                      float* __restrict__ wout,
                                                      float* __restrict__ muout) {
    const int g = threadIdx.x;
    if (g >= NGROUPS) return;

    float mu[GS];
#pragma unroll
    for (int j = 0; j < GS; ++j) mu[j] = sums[g * GS + j] * (1.0f / (float)NTOT);

    float S[TRI];
#pragma unroll
    for (int i = 0; i < GS; ++i) {
#pragma unroll
        for (int j = 0; j <= i; ++j) {
            float sg = (gram[g * TRI + tidx(i, j)] - (float)NTOT * mu[i] * mu[j])
                       * (1.0f / (float)(NTOT - 1));
            sg *= (1.0f - EPS_W);
            if (i == j) sg += EPS_W;
            S[tidx(i, j)] = sg;
        }
    }

#pragma unroll
    for (int c = 0; c < GS; ++c) {
        float d = S[tidx(c, c)];
#pragma unroll
        for (int k = 0; k < c; ++k) d -= S[tidx(c, k)] * S[tidx(c, k)];
        d = sqrtf(d);
        S[tidx(c, c)] = d;
        const float inv = 1.0f / d;
#pragma unroll
        for (int i = c + 1; i < GS; ++i) {
            float t = S[tidx(i, c)];
#pragma unroll
            for (int k = 0; k < c; ++k) t -= S[tidx(i, k)] * S[tidx(c, k)];
            S[tidx(i, c)] = t * inv;
        }
    }

#pragma unroll
    for (int c = 0; c < GS; ++c) {
        const float wcc = 1.0f / S[tidx(c, c)];
        S[tidx(c, c)] = wcc;
#pragma unroll
        for (int i = c + 1; i < GS; ++i) {
            float a = 0.0f;
#pragma unroll
            for (int k = c; k < i; ++k) a += S[tidx(i, k)] * S[tidx(k, c)];
            S[tidx(i, c)] = -a / S[tidx(i, i)];
        }
    }

#pragma unroll
    for (int k = 0; k < TRI; ++k) wout[g * TRI + k] = S[k];
#pragma unroll
    for (int j = 0; j < GS; ++j) muout[g * GS + j] = mu[j];
}

// ---------------------------------------------------------------------------
// Pass 3: out = W*(x-mu). Same pure-TLP streaming structure. Mean folded into
// per-row constant c_i = sum_j W_ij mu_j, so o_i = sum_j W_ij x_j - c_i.
// wv[136]+cb[16]+v[32] ~ 190 VGPR -> fits the 256 budget, no spill.
// ---------------------------------------------------------------------------
__global__ __launch_bounds__(256, 2) void whiten_apply(const float2* __restrict__ x2,
                                                       const float* __restrict__ wmat,
                                                       const float* __restrict__ muv,
                                                       float2* __restrict__ out2) {
    const int b = blockIdx.x, g = blockIdx.y;
    const int tid = threadIdx.x;

    float wv[TRI], cb[GS];
#pragma unroll
    for (int k = 0; k < TRI; ++k) wv[k] = wmat[g * TRI + k];
#pragma unroll
    for (int i = 0; i < GS; ++i) {
        float c = 0.0f;
#pragma unroll
        for (int j = 0; j <= i; ++j) c = fmaf(wv[tidx(i, j)], muv[g * GS + j], c);
        cb[i] = c;
    }

    const size_t off0 = ((size_t)b * D_FEAT + (size_t)g * GS) * HW2;
    const float2* base = x2 + off0;
    float2* obase = out2 + off0;

#pragma unroll 1
    for (int p = tid; p < HW2; p += 256) {
        float2 v[GS];
#pragma unroll
        for (int j = 0; j < GS; ++j) v[j] = base[(size_t)j * HW2 + p];
#pragma unroll
        for (int i = 0; i < GS; ++i) {
            float2 o;
            o.x = -cb[i];
            o.y = -cb[i];
#pragma unroll
            for (int j = 0; j <= i; ++j) {
                const float wc = wv[tidx(i, j)];
                o.x = fmaf(wc, v[j].x, o.x);
                o.y = fmaf(wc, v[j].y, o.y);
            }
            obase[(size_t)i * HW2 + p] = o;
        }
    }
}

extern "C" void kernel_launch(void* const* d_in, const int* in_sizes, int n_in,
                              void* d_out, int out_size, void* d_ws, size_t ws_size,
                              hipStream_t stream) {
    const float* x = (const float*)d_in[0];
    float* out = (float*)d_out;

    float* ws = (float*)d_ws;
    float* sums = ws;                   // 256 floats
    float* gram = ws + 256;             // 2176 floats
    float* wmat = ws + 256 + 2176;      // 2176 floats
    float* muv  = wmat + 2176;          // 256 floats

    // accumulators must start at zero (ws is poisoned each call)
    hipMemsetAsync(ws, 0, (256 + 2176) * sizeof(float), stream);

    dim3 grid(M_BATCH, NGROUPS);
    whiten_stats<<<grid, 256, 0, stream>>>((const float2*)x, sums, gram);
    whiten_solve<<<1, 64, 0, stream>>>(sums, gram, wmat, muv);
    whiten_apply<<<grid, 256, 0, stream>>>((const float2*)x, wmat, muv, (float2*)out);
}